// Round 4
// baseline (233.486 us; speedup 1.0000x reference)
//
#include <hip/hip_runtime.h>
#include <hip/hip_cooperative_groups.h>

namespace cg = cooperative_groups;

// (B,N,D,H,K) = (8,128,256,128,8) — all fp32
#define PB 8
#define PN 128
#define PD 256
#define PH 128
#define PK 8
#define D2 (2*PD)  // 512

// ===========================================================================
// Phase bodies (shared by the fused cooperative kernel and the 3-launch
// fallback). All are the r3-verified implementations.
// ===========================================================================

// prep: blocks 0..63 transpose W1[h][d2] -> W1t4[dq][h] (float4 of 4 d's per
// h) via padded 32x32 LDS tile; blocks 64..71 compute Wq[h][k], bq[k].
__device__ __forceinline__ void prep_phase(
        const float* __restrict__ W1, const float* __restrict__ W2,
        const float* __restrict__ b2, const float* __restrict__ q,
        float4* __restrict__ W1t4, float* __restrict__ Wq, float* __restrict__ bq,
        int blk, int t, float* sm /*[32*33]*/, float* red /*[256]*/)
{
    if (blk < 64) {
        const int h0 = (blk >> 4) * 32;       // 4 h-tiles
        const int d0 = (blk & 15) * 32;       // 16 d-tiles
        const int tx = t & 31, ty = t >> 5;   // ty in [0,8)
        #pragma unroll
        for (int r = 0; r < 4; ++r)
            sm[(ty + 8 * r) * 33 + tx] = W1[(h0 + ty + 8 * r) * D2 + d0 + tx];
        __syncthreads();
        const int hl = t & 31, dql = t >> 5;  // dql in [0,8)
        float4 w = make_float4(sm[hl * 33 + dql * 4 + 0], sm[hl * 33 + dql * 4 + 1],
                               sm[hl * 33 + dql * 4 + 2], sm[hl * 33 + dql * 4 + 3]);
        W1t4[((d0 >> 2) + dql) * PH + h0 + hl] = w;   // lanes consecutive in h
    } else if (blk < 72) {
        const int k = blk - 64;
        float* qs = sm;                        // reuse: first 256 floats
        qs[t] = q[k * PD + t];
        __syncthreads();
        if (t < PH) {
            float acc = 0.f;
            #pragma unroll 4
            for (int d = 0; d < PD; ++d)
                acc = fmaf(W2[d * PH + t], qs[d], acc);   // coalesced over t=h
            Wq[t * PK + k] = acc;                          // [h][k]
        }
        red[t] = b2[t] * qs[t];
        __syncthreads();
        for (int st = 128; st > 0; st >>= 1) {
            if (t < st) red[t] += red[t + st];
            __syncthreads();
        }
        if (t == 0) bq[k] = red[0];
    }
}

// proj: 512 blocks = (b:8, part:2, rg:32), 4 E-rows per block. Wave-halves
// split the dq range (s=0: 0..31, s=1: 32..63): W L2 traffic 64 MB total.
// W column coalesced float4; E rows wave-uniform (scalar path). Partials
// combined via 2 KB LDS float4 buffer (1 barrier, conflict-free).
__device__ __forceinline__ void proj_phase(
        const float* __restrict__ E, const float* __restrict__ b1,
        const float4* __restrict__ W1t4,
        float* __restrict__ Ai, float* __restrict__ Ajt,
        int blk, int t, float4* psum /*[PH]*/)
{
    const int b    = blk >> 6;
    const int part = (blk >> 5) & 1;
    const int rg   = blk & 31;
    const int h    = t & (PH - 1);
    const int s    = t >> 7;                  // dq-half selector (wave-uniform)
    const int n0   = rg * 4;

    const int ebase = __builtin_amdgcn_readfirstlane((b * PN + n0) * PD + s * 128);
    const float* e0 = E + ebase;              // uniform per wave -> s_load path
    const float* e1 = e0 + PD;
    const float* e2 = e1 + PD;
    const float* e3 = e2 + PD;
    const float4* wp = W1t4 + (part * 64 + s * 32) * PH + h;  // coalesced

    float a0 = 0.f, a1 = 0.f, a2 = 0.f, a3 = 0.f;
    #pragma unroll 8
    for (int dq = 0; dq < 32; ++dq) {
        const float4 w  = wp[dq * PH];        // 16B/lane from L2
        const float4 p0 = *reinterpret_cast<const float4*>(e0 + dq * 4);
        const float4 p1 = *reinterpret_cast<const float4*>(e1 + dq * 4);
        const float4 p2 = *reinterpret_cast<const float4*>(e2 + dq * 4);
        const float4 p3 = *reinterpret_cast<const float4*>(e3 + dq * 4);
        a0 = fmaf(w.x, p0.x, a0); a0 = fmaf(w.y, p0.y, a0);
        a0 = fmaf(w.z, p0.z, a0); a0 = fmaf(w.w, p0.w, a0);
        a1 = fmaf(w.x, p1.x, a1); a1 = fmaf(w.y, p1.y, a1);
        a1 = fmaf(w.z, p1.z, a1); a1 = fmaf(w.w, p1.w, a1);
        a2 = fmaf(w.x, p2.x, a2); a2 = fmaf(w.y, p2.y, a2);
        a2 = fmaf(w.z, p2.z, a2); a2 = fmaf(w.w, p2.w, a2);
        a3 = fmaf(w.x, p3.x, a3); a3 = fmaf(w.y, p3.y, a3);
        a3 = fmaf(w.z, p3.z, a3); a3 = fmaf(w.w, p3.w, a3);
    }

    if (s == 1)                                // stride-16B: bank-exact
        psum[h] = make_float4(a0, a1, a2, a3);
    __syncthreads();
    if (s == 0) {
        const float4 p = psum[h];
        a0 += p.x; a1 += p.y; a2 += p.z; a3 += p.w;
        if (part == 0) {
            const float bb = b1[h];
            Ai[(b * PN + n0 + 0) * PH + h] = a0 + bb;   // coalesced over h
            Ai[(b * PN + n0 + 1) * PH + h] = a1 + bb;
            Ai[(b * PN + n0 + 2) * PH + h] = a2 + bb;
            Ai[(b * PN + n0 + 3) * PH + h] = a3 + bb;
        } else {
            *reinterpret_cast<float4*>(&Ajt[(b * PH + h) * PN + n0]) =
                make_float4(a0, a1, a2, a3);
        }
    }
}

// score: 512 blocks = (b:8, i-pair:64). Thread: i = 2*ip + (t>>7), j = t&127;
// all 8 k fused. Uniform operands (Ai row, Wq, bq) via scalar/broadcast path;
// Ajt coalesced over j.
__device__ __forceinline__ void score_phase(
        const float* __restrict__ Ai, const float* __restrict__ Ajt,
        const float4* __restrict__ Wq4, const float* __restrict__ bq,
        float* __restrict__ out, int blk, int t)
{
    const int b  = blk >> 6;                  // [0,8)
    const int ip = blk & 63;
    const int il = t >> 7;                    // wave-uniform
    const int i  = ip * 2 + il;
    const int j  = t & (PN - 1);

    const int aib = __builtin_amdgcn_readfirstlane((b * PN + i) * PH);
    const float* ai = Ai + aib;               // uniform -> s_load
    const float* aj = Ajt + b * PH * PN + j;  // lane-contiguous per h

    float acc[PK];
    #pragma unroll
    for (int k = 0; k < PK; ++k) acc[k] = bq[k];

    #pragma unroll 8
    for (int hh = 0; hh < PH; ++hh) {
        const float a = ai[hh];                    // uniform b32
        const float g = aj[hh * PN];               // coalesced 256B/wave
        const float v = fmaxf(a + g, 0.f);
        const float4 wA = Wq4[hh * 2];             // uniform b128
        const float4 wB = Wq4[hh * 2 + 1];
        acc[0] = fmaf(v, wA.x, acc[0]); acc[1] = fmaf(v, wA.y, acc[1]);
        acc[2] = fmaf(v, wA.z, acc[2]); acc[3] = fmaf(v, wA.w, acc[3]);
        acc[4] = fmaf(v, wB.x, acc[4]); acc[5] = fmaf(v, wB.y, acc[5]);
        acc[6] = fmaf(v, wB.z, acc[6]); acc[7] = fmaf(v, wB.w, acc[7]);
    }

    #pragma unroll
    for (int k = 0; k < PK; ++k) {
        float sg = 1.f / (1.f + __expf(-acc[k]));
        if (j == i) sg = 0.f;
        out[((b * PK + k) * PN + i) * PN + j] = sg;   // coalesced over j
    }
}

// ===========================================================================
// Fused cooperative kernel: one launch, two grid barriers.
// 512 blocks x 256 threads, 2 blocks/CU co-resident (=512 on 256 CUs).
// ===========================================================================
__global__ __launch_bounds__(256, 2) void fused_all(
        const float* __restrict__ E,  const float* __restrict__ W1,
        const float* __restrict__ b1, const float* __restrict__ W2,
        const float* __restrict__ b2, const float* __restrict__ q,
        float4* __restrict__ W1t4, float* __restrict__ Wq, float* __restrict__ bq,
        float* __restrict__ Ai, float* __restrict__ Ajt, float* __restrict__ out)
{
    __shared__ float  sm[32 * 33];   // 4.2 KB (prep)
    __shared__ float  red[256];      // 1 KB   (prep)
    __shared__ float4 psum[PH];      // 2 KB   (proj)

    const int blk = blockIdx.x, t = threadIdx.x;

    prep_phase(W1, W2, b2, q, W1t4, Wq, bq, blk, t, sm, red);
    cg::this_grid().sync();
    proj_phase(E, b1, W1t4, Ai, Ajt, blk, t, psum);
    cg::this_grid().sync();
    score_phase(Ai, Ajt, (const float4*)Wq, bq, out, blk, t);
}

// ===========================================================================
// Fallback path: the proven 3-launch pipeline (used only if cooperative
// launch is rejected by the runtime / capture).
// ===========================================================================
__global__ __launch_bounds__(256) void k0_prep(
        const float* __restrict__ W1, const float* __restrict__ W2,
        const float* __restrict__ b2, const float* __restrict__ q,
        float4* __restrict__ W1t4, float* __restrict__ Wq, float* __restrict__ bq)
{
    __shared__ float sm[32 * 33];
    __shared__ float red[256];
    prep_phase(W1, W2, b2, q, W1t4, Wq, bq, blockIdx.x, threadIdx.x, sm, red);
}

__global__ __launch_bounds__(256, 2) void k1_proj(
        const float* __restrict__ E, const float* __restrict__ b1,
        const float4* __restrict__ W1t4,
        float* __restrict__ Ai, float* __restrict__ Ajt)
{
    __shared__ float4 psum[PH];
    proj_phase(E, b1, W1t4, Ai, Ajt, blockIdx.x, threadIdx.x, psum);
}

__global__ __launch_bounds__(256, 2) void k2_score(
        const float* __restrict__ Ai, const float* __restrict__ Ajt,
        const float4* __restrict__ Wq4, const float* __restrict__ bq,
        float* __restrict__ out)
{
    score_phase(Ai, Ajt, Wq4, bq, out, blockIdx.x, threadIdx.x);
}

extern "C" void kernel_launch(void* const* d_in, const int* in_sizes, int n_in,
                              void* d_out, int out_size, void* d_ws, size_t ws_size,
                              hipStream_t stream) {
    const float* E  = (const float*)d_in[0];
    const float* W1 = (const float*)d_in[1];
    const float* b1 = (const float*)d_in[2];
    const float* W2 = (const float*)d_in[3];
    const float* b2 = (const float*)d_in[4];
    const float* q  = (const float*)d_in[5];

    float*  Ai   = (float*)d_ws;                   // B*N*H          (512 KB)
    float*  Ajt  = Ai + PB * PN * PH;              // B*H*N          (512 KB)
    float4* W1t4 = (float4*)(Ajt + PB * PH * PN);  // 128 dq x 128 h (256 KB)
    float*  Wq   = (float*)(W1t4 + 128 * PH);      // H*K (16B-aligned)
    float*  bq   = Wq + PH * PK;                   // K
    float*  out  = (float*)d_out;

    void* args[] = { (void*)&E, (void*)&W1, (void*)&b1, (void*)&W2,
                     (void*)&b2, (void*)&q,  (void*)&W1t4, (void*)&Wq,
                     (void*)&bq, (void*)&Ai, (void*)&Ajt, (void*)&out };

    hipError_t err = hipLaunchCooperativeKernel(
        (const void*)fused_all, dim3(512), dim3(256), args, 0, stream);
    if (err != hipSuccess) {
        (void)hipGetLastError();   // clear sticky error, use fallback path
        k0_prep<<<72,  256, 0, stream>>>(W1, W2, b2, q, W1t4, Wq, bq);
        k1_proj<<<512, 256, 0, stream>>>(E, b1, W1t4, Ai, Ajt);
        k2_score<<<512, 256, 0, stream>>>(Ai, Ajt, (const float4*)Wq, bq, out);
    }
}

// Round 5
// 93.870 us; speedup vs baseline: 2.4873x; 2.4873x over previous
//
#include <hip/hip_runtime.h>

// (B,N,D,H,K) = (8,128,256,128,8) — all fp32
#define PB 8
#define PN 128
#define PD 256
#define PH 128
#define PK 8
#define D2 (2*PD)  // 512

// ---------------------------------------------------------------------------
// kA: 264 blocks, 256 threads.
//   Blocks 0..255: proj = (b:8, part:2, rg:16), 8 E-rows per block.
//     In-block W transpose: two 64-KB LDS phases. Phase p stages the part's
//     d-range [p*128, p*128+128) as float4 cells wlds[dql][h ^ (dql&7)]
//     (coalesced global float4 reads along d; XOR keeps both the staging
//     write and the compute read conflict-free). Inner loop: 1 ds_read_b128
//     (lanes along h = permutation, conflict-free) + 4 uniform E float4
//     (scalar path) per 16 FMAs. Wave-halves split rows (s=0: n0..n0+3,
//     s=1: n0+4..n0+7) so every thread owns its full d-reduction — no
//     cross-thread combine.
//     W L2 traffic: 128 blocks/part x 128 KB x 2 = 32 MB (~0.9 us) < VALU
//     floor (134M FMA ~ 1.7 us).
//     part 0 -> Ai[b][n][h] (+b1, coalesced over h); part 1 -> Ajt[b][h][n].
//   Blocks 256..263: Wq[h][k] = sum_d W2[d][h] q[k][d]; bq[k] = b2 . q[k].
// ---------------------------------------------------------------------------
__global__ __launch_bounds__(256) void kA_proj(
        const float* __restrict__ E,  const float* __restrict__ W1,
        const float* __restrict__ b1, const float* __restrict__ W2,
        const float* __restrict__ b2, const float* __restrict__ q,
        float* __restrict__ Ai, float* __restrict__ Ajt,
        float* __restrict__ Wq, float* __restrict__ bq)
{
    __shared__ float4 wlds[32 * 128];          // 64 KB
    const int blk = blockIdx.x, t = threadIdx.x;

    if (blk < 256) {
        const int b    = blk >> 5;
        const int part = (blk >> 4) & 1;
        const int rg   = blk & 15;             // 8-row group
        const int h    = t & (PH - 1);
        const int s    = t >> 7;               // row-half (wave-uniform)
        const int n0   = rg * 8 + s * 4;       // this thread's first row

        const int ebase = __builtin_amdgcn_readfirstlane((b * PN + n0) * PD);
        const float* e0 = E + ebase;           // uniform per wave -> s_load
        const float* e1 = e0 + PD;
        const float* e2 = e1 + PD;
        const float* e3 = e2 + PD;

        // staging coords (independent of compute coords)
        const int dql = t & 31;                // 0..31
        const int h2  = t >> 5;                // 0..7

        float a0 = 0.f, a1 = 0.f, a2 = 0.f, a3 = 0.f;

        #pragma unroll
        for (int p = 0; p < 2; ++p) {
            const int dqb = p * 32;            // d-range [dqb*4, dqb*4+128)
            // ---- stage: 16 float4 per thread, coalesced 512B runs ----
            const float* wsrc = W1 + part * PD + (dqb + dql) * 4;
            float4* wdst = &wlds[dql * 128];
            #pragma unroll
            for (int r = 0; r < 16; ++r) {
                const int hh = h2 * 16 + r;
                wdst[hh ^ (dql & 7)] =
                    *reinterpret_cast<const float4*>(wsrc + hh * D2);
            }
            __syncthreads();
            // ---- compute: 32 dq x (1 LDS b128 + 4 uniform E + 16 FMA) ----
            #pragma unroll 4
            for (int dq = 0; dq < 32; ++dq) {
                const float4 w = wlds[dq * 128 + (h ^ (dq & 7))];
                const int dd = (dqb + dq) * 4;
                const float4 p0 = *reinterpret_cast<const float4*>(e0 + dd);
                const float4 p1 = *reinterpret_cast<const float4*>(e1 + dd);
                const float4 p2 = *reinterpret_cast<const float4*>(e2 + dd);
                const float4 p3 = *reinterpret_cast<const float4*>(e3 + dd);
                a0 = fmaf(w.x, p0.x, a0); a0 = fmaf(w.y, p0.y, a0);
                a0 = fmaf(w.z, p0.z, a0); a0 = fmaf(w.w, p0.w, a0);
                a1 = fmaf(w.x, p1.x, a1); a1 = fmaf(w.y, p1.y, a1);
                a1 = fmaf(w.z, p1.z, a1); a1 = fmaf(w.w, p1.w, a1);
                a2 = fmaf(w.x, p2.x, a2); a2 = fmaf(w.y, p2.y, a2);
                a2 = fmaf(w.z, p2.z, a2); a2 = fmaf(w.w, p2.w, a2);
                a3 = fmaf(w.x, p3.x, a3); a3 = fmaf(w.y, p3.y, a3);
                a3 = fmaf(w.z, p3.z, a3); a3 = fmaf(w.w, p3.w, a3);
            }
            __syncthreads();                   // WAR before next stage
        }

        if (part == 0) {
            const float bb = b1[h];
            Ai[(b * PN + n0 + 0) * PH + h] = a0 + bb;   // coalesced over h
            Ai[(b * PN + n0 + 1) * PH + h] = a1 + bb;
            Ai[(b * PN + n0 + 2) * PH + h] = a2 + bb;
            Ai[(b * PN + n0 + 3) * PH + h] = a3 + bb;
        } else {
            *reinterpret_cast<float4*>(&Ajt[(b * PH + h) * PN + n0]) =
                make_float4(a0, a1, a2, a3);
        }
    } else {
        // ---- Wq / bq (8 blocks) ----
        float* smf = reinterpret_cast<float*>(wlds);
        float* qs  = smf;                      // [PD]
        float* red = smf + PD;                 // [256]
        const int k = blk - 256;
        qs[t] = q[k * PD + t];
        __syncthreads();
        if (t < PH) {
            float acc = 0.f;
            #pragma unroll 4
            for (int d = 0; d < PD; ++d)
                acc = fmaf(W2[d * PH + t], qs[d], acc);   // coalesced over t=h
            Wq[t * PK + k] = acc;                          // [h][k]
        }
        red[t] = b2[t] * qs[t];
        __syncthreads();
        for (int st = 128; st > 0; st >>= 1) {
            if (t < st) red[t] += red[t + st];
            __syncthreads();
        }
        if (t == 0) bq[k] = red[0];
    }
}

// ---------------------------------------------------------------------------
// kB: 512 blocks = (b:8, i-pair:64), 2 blocks/CU. Thread: i = 2*ip + (t>>7),
//   j = t&127; all 8 k fused (8 accs). Uniform operands (Ai row, Wq, bq) via
//   scalar/broadcast path (no LDS, no barriers); Ajt coalesced over j.
// ---------------------------------------------------------------------------
__global__ __launch_bounds__(256, 2) void kB_score(
        const float* __restrict__ Ai, const float* __restrict__ Ajt,
        const float4* __restrict__ Wq4, const float* __restrict__ bq,
        float* __restrict__ out)
{
    const int blk = blockIdx.x, t = threadIdx.x;
    const int b  = blk >> 6;                  // [0,8)
    const int ip = blk & 63;
    const int il = t >> 7;                    // wave-uniform
    const int i  = ip * 2 + il;
    const int j  = t & (PN - 1);

    const int aib = __builtin_amdgcn_readfirstlane((b * PN + i) * PH);
    const float* ai = Ai + aib;               // uniform -> s_load
    const float* aj = Ajt + b * PH * PN + j;  // lane-contiguous per h

    float acc[PK];
    #pragma unroll
    for (int k = 0; k < PK; ++k) acc[k] = bq[k];

    #pragma unroll 8
    for (int hh = 0; hh < PH; ++hh) {
        const float a = ai[hh];                    // uniform b32
        const float g = aj[hh * PN];               // coalesced 256B/wave
        const float v = fmaxf(a + g, 0.f);
        const float4 wA = Wq4[hh * 2];             // uniform b128
        const float4 wB = Wq4[hh * 2 + 1];
        acc[0] = fmaf(v, wA.x, acc[0]); acc[1] = fmaf(v, wA.y, acc[1]);
        acc[2] = fmaf(v, wA.z, acc[2]); acc[3] = fmaf(v, wA.w, acc[3]);
        acc[4] = fmaf(v, wB.x, acc[4]); acc[5] = fmaf(v, wB.y, acc[5]);
        acc[6] = fmaf(v, wB.z, acc[6]); acc[7] = fmaf(v, wB.w, acc[7]);
    }

    #pragma unroll
    for (int k = 0; k < PK; ++k) {
        float sg = 1.f / (1.f + __expf(-acc[k]));
        if (j == i) sg = 0.f;
        out[((b * PK + k) * PN + i) * PN + j] = sg;   // coalesced over j
    }
}

extern "C" void kernel_launch(void* const* d_in, const int* in_sizes, int n_in,
                              void* d_out, int out_size, void* d_ws, size_t ws_size,
                              hipStream_t stream) {
    const float* E  = (const float*)d_in[0];
    const float* W1 = (const float*)d_in[1];
    const float* b1 = (const float*)d_in[2];
    const float* W2 = (const float*)d_in[3];
    const float* b2 = (const float*)d_in[4];
    const float* q  = (const float*)d_in[5];

    float* Ai  = (float*)d_ws;                 // B*N*H (512 KB)
    float* Ajt = Ai + PB * PN * PH;            // B*H*N (512 KB)
    float* Wq  = Ajt + PB * PH * PN;           // H*K (16B-aligned)
    float* bq  = Wq + PH * PK;                 // K

    kA_proj<<<264, 256, 0, stream>>>(E, W1, b1, W2, b2, q, Ai, Ajt, Wq, bq);
    kB_score<<<512, 256, 0, stream>>>(Ai, Ajt, (const float4*)Wq, bq, (float*)d_out);
}